// Round 5
// baseline (29.153 us; speedup 1.0000x reference)
//
#include <hip/hip_runtime.h>
#include <math.h>

#define HDIM 224
#define WDIM 224
#define HW (HDIM * WDIM)
#define OH 220
#define OW 220
#define NCOL 30
#define SROWS 10               // output rows per strip (220 = 22*10, exact cover)
#define NSTRIP 22
#define LROWS 14               // input rows per strip
#define NORM_INV (1.0f / (25.0f * 768.0f))

__device__ __forceinline__ float4 ld4(const float* p) {
    return *reinterpret_cast<const float4*>(p);
}

// 2 waves per block; each wave owns one (image b, color c, 10-row strip).
// No LDS, no barriers, no cross-lane ops: each lane loads its own 8 input
// columns (overlapping the neighbor's span) and computes 8 distances.
__global__ __launch_bounds__(128) void rgb_conv2d_kernel(
    const float* __restrict__ in,   // [B,3,224,224]
    const float* __restrict__ wt,   // [30,3,5,5] (color constant over window)
    float* __restrict__ out)        // [B,30,220,220]
{
    const int gid  = blockIdx.x;         // 0..2639
    const int b    = gid & 7;            // XCD-affine: image b -> one XCD's L2
    const int k    = gid >> 3;           // 0..329
    const int c    = k / (NSTRIP / 2);   // 0..29
    const int sp   = k - c * (NSTRIP / 2);
    const int wid  = threadIdx.x >> 6;   // 0/1
    const int lane = threadIdx.x & 63;
    const int s    = 2 * sp + wid;       // 0..21

    const bool act = lane < 55;          // lane covers output cols 4l..4l+3

    const float* base = in + (size_t)b * 3 * HW
                      + (size_t)(SROWS * s) * WDIM + 4 * lane;
    float* ob = out + ((size_t)(b * NCOL + c) * OH + SROWS * s) * OW + 4 * lane;

    const float R2 = wt[c * 75 +  0] * 255.0f;
    const float G2 = wt[c * 75 + 25] * 255.0f;
    const float B2 = wt[c * 75 + 50] * 255.0f;
    const float kR  = fmaf(R2, 1.0f / 512.0f, 2.0f);
    const float CC  = 4.0f + 255.0f / 256.0f;
    const float mR2 = -R2, mG2 = -2.0f * G2, mB2 = -B2;

    auto dist = [&](float xr, float xg, float xb) -> float {
        float dR  = fmaf(xr, 255.0f, mR2);
        float cR  = fmaf(xr, 255.0f / 512.0f, kR);
        float cB  = CC - cR;
        float dG2 = fmaf(xg, 510.0f, mG2);
        float dB  = fmaf(xb, 255.0f, mB2);
        float t   = fmaf(cR * dR, dR, 1e-8f);
        t = fmaf(dG2, dG2, t);
        t = fmaf(cB * dB, dB, t);
        return __builtin_amdgcn_sqrtf(t);
    };

    float4 h0, h1, h2, h3, h4;   // 5-deep ring of horizontal 5-sums

    #pragma unroll
    for (int r = 0; r < LROWS; ++r) {
        float4 hn = make_float4(0.f, 0.f, 0.f, 0.f);
        if (act) {
            const float* rp = base + r * WDIM;
            float4 a0 = ld4(rp);          float4 a1 = ld4(rp + 4);
            float4 g0 = ld4(rp + HW);     float4 g1 = ld4(rp + HW + 4);
            float4 b0 = ld4(rp + 2*HW);   float4 b1 = ld4(rp + 2*HW + 4);
            float d0 = dist(a0.x, g0.x, b0.x);
            float d1 = dist(a0.y, g0.y, b0.y);
            float d2 = dist(a0.z, g0.z, b0.z);
            float d3 = dist(a0.w, g0.w, b0.w);
            float d4 = dist(a1.x, g1.x, b1.x);
            float d5 = dist(a1.y, g1.y, b1.y);
            float d6 = dist(a1.z, g1.z, b1.z);
            float d7 = dist(a1.w, g1.w, b1.w);
            hn.x = ((d0 + d1) + (d2 + d3)) + d4;
            hn.y = hn.x - d0 + d5;
            hn.z = hn.y - d1 + d6;
            hn.w = hn.z - d2 + d7;
        }
        h0 = h1; h1 = h2; h2 = h3; h3 = h4; h4 = hn;   // rotate (register rename)

        if (r >= 4 && act) {
            float4 o;
            o.x = (((h0.x + h1.x) + (h2.x + h3.x)) + h4.x) * NORM_INV;
            o.y = (((h0.y + h1.y) + (h2.y + h3.y)) + h4.y) * NORM_INV;
            o.z = (((h0.z + h1.z) + (h2.z + h3.z)) + h4.z) * NORM_INV;
            o.w = (((h0.w + h1.w) + (h2.w + h3.w)) + h4.w) * NORM_INV;
            *reinterpret_cast<float4*>(ob + (size_t)(r - 4) * OW) = o;
        }
    }
}

extern "C" void kernel_launch(void* const* d_in, const int* in_sizes, int n_in,
                              void* d_out, int out_size, void* d_ws, size_t ws_size,
                              hipStream_t stream) {
    const float* in = (const float*)d_in[0];
    const float* wt = (const float*)d_in[1];
    float* out = (float*)d_out;

    const int B = in_sizes[0] / (3 * HW);                // 8
    const int nblocks = B * NCOL * (NSTRIP / 2);         // 2640 blocks x 128 thr
    rgb_conv2d_kernel<<<dim3(nblocks), dim3(128), 0, stream>>>(in, wt, out);
}

// Round 6
// 21.151 us; speedup vs baseline: 1.3783x; 1.3783x over previous
//
#include <hip/hip_runtime.h>
#include <math.h>

#define HDIM 224
#define WDIM 224
#define HW (HDIM * WDIM)
#define OH 220
#define OW 220
#define NCOL 30
#define TY 16               // output rows per block
#define DROWS 20            // TY + 4 input/D rows
#define NC4 56              // float4 cells per D row (224 cols)
#define NCELL (DROWS * NC4) // 1120
#define LSTR 228            // LDS row stride in words (224 + 4 pad)
#define NORM_INV (1.0f / (25.0f * 768.0f))

__device__ __forceinline__ float4 ld4(const float* p) {
    return *reinterpret_cast<const float4*>(p);
}

__global__ __launch_bounds__(256) void rgb_conv2d_kernel(
    const float* __restrict__ in,   // [B,3,224,224]
    const float* __restrict__ wt,   // [30,3,5,5] (color constant over window)
    float* __restrict__ out)        // [B,30,220,220]
{
    __shared__ float Dd[DROWS * LSTR];   // 18240 B -> 8 blocks/CU

    const int tid = threadIdx.x;
    const int by  = blockIdx.x;          // 0..13
    const int bc  = blockIdx.y;          // b*30 + c
    const int y0  = (by < 13) ? by * TY : (OH - TY);   // {0,16,...,192,204}
    const int b   = bc / NCOL;
    const int c   = bc - b * NCOL;

    const float* inb = in + (size_t)b * 3 * HW;
    const float R2 = wt[c * 75 +  0] * 255.0f;
    const float G2 = wt[c * 75 + 25] * 255.0f;
    const float B2 = wt[c * 75 + 50] * 255.0f;
    // d^2 = cR*dR^2 + (2dG)^2 + cB*dB^2 + eps; x255 folded into fma constants
    const float kR  = fmaf(R2, 1.0f / 512.0f, 2.0f);
    const float CC  = 4.0f + 255.0f / 256.0f;
    const float mR2 = -R2, mG2 = -2.0f * G2, mB2 = -B2;

    auto dist = [&](float xr, float xg, float xb) -> float {
        float dR  = fmaf(xr, 255.0f, mR2);
        float cR  = fmaf(xr, 255.0f / 512.0f, kR);
        float cB  = CC - cR;
        float dG2 = fmaf(xg, 510.0f, mG2);
        float dB  = fmaf(xb, 255.0f, mB2);
        float t   = fmaf(cR * dR, dR, 1e-8f);
        t = fmaf(dG2, dG2, t);
        t = fmaf(cB * dB, dB, t);
        return __builtin_amdgcn_sqrtf(t);
    };

    // ---- Pass 1: distance tile (20 rows x 224 cols), float4 cells, 1120 total
    #pragma unroll
    for (int p = 0; p < 5; ++p) {
        int idx = tid + p * 256;
        if (p < 4 || idx < NCELL) {
            int row  = idx / NC4;
            int col4 = idx - row * NC4;
            const float* src = inb + (y0 + row) * WDIM + 4 * col4;
            float4 Pr = ld4(src);
            float4 Pg = ld4(src + HW);
            float4 Pb = ld4(src + 2 * HW);
            float4 dq;
            dq.x = dist(Pr.x, Pg.x, Pb.x);
            dq.y = dist(Pr.y, Pg.y, Pb.y);
            dq.z = dist(Pr.z, Pg.z, Pb.z);
            dq.w = dist(Pr.w, Pg.w, Pb.w);
            *reinterpret_cast<float4*>(&Dd[row * LSTR + 4 * col4]) = dq;
        }
    }
    __syncthreads();

    // ---- Pass 2: thread -> 4-wide x 4-tall output patch.
    // 16 independent b128 LDS reads (8 rows x 2), then register-only math.
    if (tid < 220) {
        const int tx = tid % 55;          // output cols 4tx..4tx+3
        const int g  = tid / 55;          // output rows 4g..4g+3
        const float* dp = &Dd[(4 * g) * LSTR + 4 * tx];

        float4 h[8];
        #pragma unroll
        for (int r = 0; r < 8; ++r) {
            float4 A  = ld4(dp + r * LSTR);
            float4 Bv = ld4(dp + r * LSTR + 4);
            h[r].x = ((A.x + A.y) + (A.z + A.w)) + Bv.x;
            h[r].y = h[r].x + (Bv.y - A.x);
            h[r].z = h[r].y + (Bv.z - A.y);
            h[r].w = h[r].z + (Bv.w - A.z);
        }

        float4 o0, o1, o2, o3;
        o0.x = (((h[0].x + h[1].x) + (h[2].x + h[3].x)) + h[4].x);
        o0.y = (((h[0].y + h[1].y) + (h[2].y + h[3].y)) + h[4].y);
        o0.z = (((h[0].z + h[1].z) + (h[2].z + h[3].z)) + h[4].z);
        o0.w = (((h[0].w + h[1].w) + (h[2].w + h[3].w)) + h[4].w);
        o1.x = o0.x - h[0].x + h[5].x;  o1.y = o0.y - h[0].y + h[5].y;
        o1.z = o0.z - h[0].z + h[5].z;  o1.w = o0.w - h[0].w + h[5].w;
        o2.x = o1.x - h[1].x + h[6].x;  o2.y = o1.y - h[1].y + h[6].y;
        o2.z = o1.z - h[1].z + h[6].z;  o2.w = o1.w - h[1].w + h[6].w;
        o3.x = o2.x - h[2].x + h[7].x;  o3.y = o2.y - h[2].y + h[7].y;
        o3.z = o2.z - h[2].z + h[7].z;  o3.w = o2.w - h[2].w + h[7].w;

        float* ob = out + ((size_t)bc * OH + (y0 + 4 * g)) * OW + 4 * tx;
        *reinterpret_cast<float4*>(ob + 0 * OW) =
            make_float4(o0.x * NORM_INV, o0.y * NORM_INV, o0.z * NORM_INV, o0.w * NORM_INV);
        *reinterpret_cast<float4*>(ob + 1 * OW) =
            make_float4(o1.x * NORM_INV, o1.y * NORM_INV, o1.z * NORM_INV, o1.w * NORM_INV);
        *reinterpret_cast<float4*>(ob + 2 * OW) =
            make_float4(o2.x * NORM_INV, o2.y * NORM_INV, o2.z * NORM_INV, o2.w * NORM_INV);
        *reinterpret_cast<float4*>(ob + 3 * OW) =
            make_float4(o3.x * NORM_INV, o3.y * NORM_INV, o3.z * NORM_INV, o3.w * NORM_INV);
    }
}

extern "C" void kernel_launch(void* const* d_in, const int* in_sizes, int n_in,
                              void* d_out, int out_size, void* d_ws, size_t ws_size,
                              hipStream_t stream) {
    const float* in = (const float*)d_in[0];
    const float* wt = (const float*)d_in[1];
    float* out = (float*)d_out;

    const int B = in_sizes[0] / (3 * HW);            // 8
    dim3 grid(14, B * NCOL);                         // 14 y-tiles x 240 (b,c)
    rgb_conv2d_kernel<<<grid, dim3(256), 0, stream>>>(in, wt, out);
}

// Round 7
// 19.714 us; speedup vs baseline: 1.4788x; 1.0729x over previous
//
#include <hip/hip_runtime.h>
#include <hip/hip_fp16.h>
#include <math.h>

#define HDIM 224
#define WDIM 224
#define HW (HDIM * WDIM)
#define OH 220
#define OW 220
#define NCOL 30
#define TY 16                 // output rows per block
#define DROWS 20              // input/D rows per block
#define NC4 56                // float4 cells per D row
#define NCELL (DROWS * NC4)   // 1120
#define WSTR 116              // LDS row stride in u32 words (224 halves + 8 pad)
#define SCALE (16.0f / (25.0f * 768.0f))   // d was computed at 1/16 scale

__device__ __forceinline__ float4 ld4(const float* p) {
    return *reinterpret_cast<const float4*>(p);
}
__device__ __forceinline__ uint32_t h2u(__half2 h) { return __builtin_bit_cast(uint32_t, h); }
__device__ __forceinline__ __half2 u2h(uint32_t u) { return __builtin_bit_cast(__half2, u); }

__global__ __launch_bounds__(256) void rgb_conv2d_kernel(
    const float* __restrict__ in,   // [B,3,224,224]
    const float* __restrict__ wt,   // [30,3,5,5] (color constant over window)
    float* __restrict__ out)        // [B,30,220,220]
{
    __shared__ uint32_t Dd[DROWS * WSTR];   // fp16 distance tile, 9280 B

    const int tid = threadIdx.x;
    const int by  = blockIdx.x;             // 0..13
    const int bc  = blockIdx.y;             // b*30 + c
    const int y0  = (by < 13) ? by * TY : (OH - TY);
    const int b   = bc / NCOL;
    const int c   = bc - b * NCOL;

    const float* inb = in + (size_t)b * 3 * HW;
    const float R2f = wt[c * 75 +  0] * 255.0f;
    const float G2f = wt[c * 75 + 25] * 255.0f;
    const float B2f = wt[c * 75 + 50] * 255.0f;

    // All distance math in packed fp16 at 1/16 scale:
    // dR' = 15.9375*r - R2/16 ; dG2' = 31.875*g - G2/8 ; dB' = 15.9375*b - B2/16
    // d'^2 = cR*dR'^2 + dG2'^2 + cB*dB'^2  (<= ~2540, fp16-safe); d = 16*d'
    const __half2 hS    = __float2half2_rn(15.9375f);
    const __half2 hSG   = __float2half2_rn(31.875f);
    const __half2 hC512 = __float2half2_rn(255.0f / 512.0f);
    const __half2 hKR   = __float2half2_rn(fmaf(R2f, 1.0f / 512.0f, 2.0f));
    const __half2 hCC   = __float2half2_rn(4.0f + 255.0f / 256.0f);
    const __half2 hmR   = __float2half2_rn(-R2f * (1.0f / 16.0f));
    const __half2 hmG   = __float2half2_rn(-G2f * (1.0f / 8.0f));
    const __half2 hmB   = __float2half2_rn(-B2f * (1.0f / 16.0f));

    auto dist2 = [&](__half2 r, __half2 g, __half2 bb) -> __half2 {
        __half2 dR = __hfma2(r, hS, hmR);
        __half2 cR = __hfma2(r, hC512, hKR);
        __half2 cB = __hsub2(hCC, cR);
        __half2 dG = __hfma2(g, hSG, hmG);
        __half2 dB = __hfma2(bb, hS, hmB);
        __half2 t  = __hmul2(__hmul2(cR, dR), dR);
        t = __hfma2(dG, dG, t);
        t = __hfma2(__hmul2(cB, dB), dB, t);
        return h2sqrt(t);
    };

    // ---- Pass 1: distance tile (20 rows x 224 cols), 4 px/thread/iter
    #pragma unroll
    for (int p = 0; p < 5; ++p) {
        int idx = tid + p * 256;
        if (p < 4 || idx < NCELL) {
            int row  = idx / NC4;
            int col4 = idx - row * NC4;
            const float* src = inb + (y0 + row) * WDIM + 4 * col4;
            float4 Pr = ld4(src);
            float4 Pg = ld4(src + HW);
            float4 Pb = ld4(src + 2 * HW);
            __half2 rA = __floats2half2_rn(Pr.x, Pr.y), rB = __floats2half2_rn(Pr.z, Pr.w);
            __half2 gA = __floats2half2_rn(Pg.x, Pg.y), gB = __floats2half2_rn(Pg.z, Pg.w);
            __half2 bA = __floats2half2_rn(Pb.x, Pb.y), bB = __floats2half2_rn(Pb.z, Pb.w);
            __half2 dA = dist2(rA, gA, bA);   // d0,d1
            __half2 dB = dist2(rB, gB, bB);   // d2,d3
            *reinterpret_cast<uint2*>(&Dd[row * WSTR + 2 * col4]) =
                make_uint2(h2u(dA), h2u(dB));
        }
    }
    __syncthreads();

    // ---- Pass 2: thread -> 4-wide x 4-tall output patch, packed fp16 sums.
    if (tid < 220) {
        const int tx = tid % 55;            // output cols 4tx..4tx+3
        const int g4 = tid / 55;            // output rows 4g..4g+3
        const uint32_t* dp = &Dd[(4 * g4) * WSTR + 2 * tx];

        __half2 HA[8], HB[8];               // h-sum pairs (h0,h1), (h2,h3) per row
        #pragma unroll
        for (int r = 0; r < 8; ++r) {
            uint2 v0 = *reinterpret_cast<const uint2*>(dp + r * WSTR);      // d0..d3
            uint2 v1 = *reinterpret_cast<const uint2*>(dp + r * WSTR + 2);  // d4..d7
            uint32_t a = v0.x, bw = v0.y, cw = v1.x, e = v1.y;
            __half2 t1 = u2h(__builtin_amdgcn_alignbit(bw, a, 16));   // (d1,d2)
            __half2 t2 = u2h(__builtin_amdgcn_alignbit(cw, bw, 16));  // (d3,d4)
            __half2 t3 = u2h(__builtin_amdgcn_alignbit(e, cw, 16));   // (d5,d6)
            __half2 s  = __hadd2(__hadd2(u2h(bw), t2), u2h(cw));      // b+t2+c
            HA[r] = __hadd2(s, __hadd2(u2h(a), t1));                  // (h0,h1)
            HB[r] = __hadd2(s, __hadd2(t3, u2h(e)));                  // (h2,h3)
        }

        __half2 VA[4], VB[4];
        VA[0] = __hadd2(__hadd2(__hadd2(HA[0], HA[1]), __hadd2(HA[2], HA[3])), HA[4]);
        VB[0] = __hadd2(__hadd2(__hadd2(HB[0], HB[1]), __hadd2(HB[2], HB[3])), HB[4]);
        VA[1] = __hadd2(__hsub2(VA[0], HA[0]), HA[5]);
        VB[1] = __hadd2(__hsub2(VB[0], HB[0]), HB[5]);
        VA[2] = __hadd2(__hsub2(VA[1], HA[1]), HA[6]);
        VB[2] = __hadd2(__hsub2(VB[1], HB[1]), HB[6]);
        VA[3] = __hadd2(__hsub2(VA[2], HA[2]), HA[7]);
        VB[3] = __hadd2(__hsub2(VB[2], HB[2]), HB[7]);

        float* ob = out + ((size_t)bc * OH + (y0 + 4 * g4)) * OW + 4 * tx;
        #pragma unroll
        for (int r = 0; r < 4; ++r) {
            float4 o = make_float4(__low2float(VA[r]) * SCALE,
                                   __high2float(VA[r]) * SCALE,
                                   __low2float(VB[r]) * SCALE,
                                   __high2float(VB[r]) * SCALE);
            *reinterpret_cast<float4*>(ob + (size_t)r * OW) = o;
        }
    }
}

extern "C" void kernel_launch(void* const* d_in, const int* in_sizes, int n_in,
                              void* d_out, int out_size, void* d_ws, size_t ws_size,
                              hipStream_t stream) {
    const float* in = (const float*)d_in[0];
    const float* wt = (const float*)d_in[1];
    float* out = (float*)d_out;

    const int B = in_sizes[0] / (3 * HW);            // 8
    dim3 grid(14, B * NCOL);                         // 14 y-tiles x 240 (b,c)
    rgb_conv2d_kernel<<<grid, dim3(256), 0, stream>>>(in, wt, out);
}